// Round 2
// baseline (76.694 us; speedup 1.0000x reference)
//
#include <hip/hip_runtime.h>
#include <hip/hip_bf16.h>

typedef __attribute__((ext_vector_type(8))) short bf16x8;
typedef __attribute__((ext_vector_type(8))) unsigned short u16x8;
typedef __attribute__((ext_vector_type(4))) float f32x4;

#define DDIM 1024
#define NROWS_X 8192
#define BM 128
#define BN 128
#define BK 32

__device__ __forceinline__ void gload_lds16(const void* g, void* l) {
  __builtin_amdgcn_global_load_lds((const __attribute__((address_space(1))) void*)g,
                                   (__attribute__((address_space(3))) void*)l,
                                   16, 0, 0);
}

__device__ __forceinline__ unsigned short f2bf(float f) {
  unsigned int u = __float_as_uint(f);
  unsigned int r = (u + 0x7FFFu + ((u >> 16) & 1u)) >> 16;   // RNE
  return (unsigned short)r;
}

// Convert f32 rows -> bf16 rows into workspace.
// Row space: [0,8192)=X, [8192,9216)=W1, [9216,9232)=W2, [9232,9248)=W3.
__global__ __launch_bounds__(256) void s6_convert(
    const float* __restrict__ X, const float* __restrict__ W1,
    const float* __restrict__ W2, const float* __restrict__ W3,
    unsigned short* __restrict__ Xbf, unsigned short* __restrict__ W1bf,
    unsigned short* __restrict__ W2bf, unsigned short* __restrict__ W3bf)
{
  const int wid = threadIdx.x >> 6, lane = threadIdx.x & 63;
  const int row = blockIdx.x * 4 + wid;
  const float* src;
  unsigned short* dst;
  if (row < 8192)      { src = X  + (size_t)row * DDIM;        dst = Xbf  + (size_t)row * DDIM; }
  else if (row < 9216) { int r = row - 8192; src = W1 + (size_t)r * DDIM; dst = W1bf + (size_t)r * DDIM; }
  else if (row < 9232) { int r = row - 9216; src = W2 + (size_t)r * DDIM; dst = W2bf + (size_t)r * DDIM; }
  else                 { int r = row - 9232; src = W3 + (size_t)r * DDIM; dst = W3bf + (size_t)r * DDIM; }

  const float4* s4 = reinterpret_cast<const float4*>(src + lane * 16);
  unsigned short u[16];
  #pragma unroll
  for (int j = 0; j < 4; ++j) {
    float4 v = s4[j];
    u[j*4+0] = f2bf(v.x); u[j*4+1] = f2bf(v.y);
    u[j*4+2] = f2bf(v.z); u[j*4+3] = f2bf(v.w);
  }
  u16x8* d8 = reinterpret_cast<u16x8*>(dst + lane * 16);
  u16x8 lo, hi;
  #pragma unroll
  for (int j = 0; j < 8; ++j) { lo[j] = u[j]; hi[j] = u[j + 8]; }
  d8[0] = lo; d8[1] = hi;
}

// s[r] = sum_n (x[r]·W2[n] + b2[n]) * (x[r]·W3[n] + b3[n]); bf16 MFMA.
__global__ __launch_bounds__(256) void s6_s_kernel(
    const unsigned short* __restrict__ Xbf,
    const unsigned short* __restrict__ W2bf,
    const float* __restrict__ b2,
    const unsigned short* __restrict__ W3bf,
    const float* __restrict__ b3,
    float* __restrict__ s_out)
{
  const int wid  = threadIdx.x >> 6;
  const int lane = threadIdx.x & 63;
  const int grp  = blockIdx.x * 4 + wid;     // 512 groups of 16 rows
  const int r0   = grp * 16;
  const int row  = lane & 15;
  const int koff = (lane >> 4) * 8;

  const f32x4 z4 = {0.f, 0.f, 0.f, 0.f};
  f32x4 accB = z4, accC = z4;

  const unsigned short* xp  = Xbf  + (size_t)(r0 + row) * DDIM + koff;
  const unsigned short* w2p = W2bf + (size_t)row * DDIM + koff;
  const unsigned short* w3p = W3bf + (size_t)row * DDIM + koff;

  #pragma unroll 4
  for (int k = 0; k < DDIM; k += 32) {
    bf16x8 a  = *reinterpret_cast<const bf16x8*>(xp  + k);
    bf16x8 f2 = *reinterpret_cast<const bf16x8*>(w2p + k);
    bf16x8 f3 = *reinterpret_cast<const bf16x8*>(w3p + k);
    accB = __builtin_amdgcn_mfma_f32_16x16x32_bf16(a, f2, accB, 0, 0, 0);
    accC = __builtin_amdgcn_mfma_f32_16x16x32_bf16(a, f3, accC, 0, 0, 0);
  }

  // acc[q] at (row=(lane>>4)*4+q, col=lane&15); col is the n-index.
  const int col = lane & 15;
  const float bb = b2[col];
  const float cb = b3[col];
  float p[4];
  #pragma unroll
  for (int q = 0; q < 4; ++q) p[q] = (accB[q] + bb) * (accC[q] + cb);
  #pragma unroll
  for (int msk = 1; msk < 16; msk <<= 1) {
    #pragma unroll
    for (int q = 0; q < 4; ++q) p[q] += __shfl_xor(p[q], msk, 64);
  }
  if (col == 0) {
    const int rbase = r0 + (lane >> 4) * 4;
    #pragma unroll
    for (int q = 0; q < 4; ++q) s_out[rbase + q] = p[q];
  }
}

// y[r][e] = x[r][e] * s[r] * softplus( sum_d x[r][d]*W1[e][d] + b1[e] )
__global__ __launch_bounds__(256) void s6_main_kernel(
    const unsigned short* __restrict__ Xbf,
    const unsigned short* __restrict__ W1bf,
    const float* __restrict__ Xf32,
    const float* __restrict__ b1,
    const float* __restrict__ s_in,
    float* __restrict__ Y)
{
  __shared__ __align__(16) unsigned short Alds[BM * BK];
  __shared__ __align__(16) unsigned short Blds[BN * BK];

  const int tid  = threadIdx.x;
  const int wid  = tid >> 6;
  const int lane = tid & 63;
  const int rb   = blockIdx.x >> 3;   // 64 row-blocks
  const int cb   = blockIdx.x & 7;    // 8 col-blocks
  const int row0 = rb * BM;
  const int col0 = cb * BN;
  const int wr = wid >> 1, wc = wid & 1;   // 2x2 waves, 64x64 each

  const f32x4 z4 = {0.f, 0.f, 0.f, 0.f};
  f32x4 acc[4][4];
  #pragma unroll
  for (int i = 0; i < 4; ++i)
    #pragma unroll
    for (int j = 0; j < 4; ++j)
      acc[i][j] = z4;

  // Staging: thread t stages 16B chunk t and t+256 of each tile.
  // chunk c -> tile row c>>2, 8-elem col (c&3)*8; LDS byte offset c*16 (linear).
  const unsigned short* ga = Xbf  + (size_t)(row0 + (tid >> 2)) * DDIM + (tid & 3) * 8;
  const unsigned short* gb = W1bf + (size_t)(col0 + (tid >> 2)) * DDIM + (tid & 3) * 8;
  unsigned short* la1 = Alds + wid * 512;          // wave-uniform base; HW adds lane*16B
  unsigned short* la2 = Alds + 2048 + wid * 512;
  unsigned short* lb1 = Blds + wid * 512;
  unsigned short* lb2 = Blds + 2048 + wid * 512;

  const int fr = lane & 15;           // fragment row within 16
  const int fk = (lane >> 4) * 8;     // k element offset

  for (int kt = 0; kt < DDIM; kt += BK) {
    __syncthreads();                  // previous compute done before overwrite
    gload_lds16(ga + kt, la1);
    gload_lds16(ga + kt + 64 * DDIM, la2);
    gload_lds16(gb + kt, lb1);
    gload_lds16(gb + kt + 64 * DDIM, lb2);
    __syncthreads();                  // drains vmcnt before barrier

    bf16x8 af[4], bfr[4];
    #pragma unroll
    for (int m = 0; m < 4; ++m)
      af[m] = *reinterpret_cast<const bf16x8*>(&Alds[(wr * 64 + m * 16 + fr) * BK + fk]);
    #pragma unroll
    for (int n = 0; n < 4; ++n)
      bfr[n] = *reinterpret_cast<const bf16x8*>(&Blds[(wc * 64 + n * 16 + fr) * BK + fk]);
    #pragma unroll
    for (int m = 0; m < 4; ++m)
      #pragma unroll
      for (int n = 0; n < 4; ++n)
        acc[m][n] = __builtin_amdgcn_mfma_f32_16x16x32_bf16(af[m], bfr[n], acc[m][n], 0, 0, 0);
  }

  // Epilogue: D mapping col=lane&15, row=(lane>>4)*4+reg.
  const int orow = (lane >> 4) * 4;
  #pragma unroll
  for (int m = 0; m < 4; ++m) {
    #pragma unroll
    for (int q = 0; q < 4; ++q) {
      const int gr = row0 + wr * 64 + m * 16 + orow + q;
      const float sv = s_in[gr];
      const size_t rbase = (size_t)gr * DDIM;
      #pragma unroll
      for (int n = 0; n < 4; ++n) {
        const int gc = col0 + wc * 64 + n * 16 + fr;
        const float z  = acc[m][n][q] + b1[gc];
        const float sp = fmaxf(z, 0.f) + log1pf(__expf(-fabsf(z)));   // stable softplus
        const float xv = Xf32[rbase + gc];
        Y[rbase + gc] = xv * sv * sp;
      }
    }
  }
}

extern "C" void kernel_launch(void* const* d_in, const int* in_sizes, int n_in,
                              void* d_out, int out_size, void* d_ws, size_t ws_size,
                              hipStream_t stream) {
  const float* x  = (const float*)d_in[0];
  const float* W1 = (const float*)d_in[1];
  const float* b1 = (const float*)d_in[2];
  const float* W2 = (const float*)d_in[3];
  const float* b2 = (const float*)d_in[4];
  const float* W3 = (const float*)d_in[5];
  const float* b3 = (const float*)d_in[6];
  // d_in[7] = A is provably unused (h is zero-initialized in the reference).

  // Workspace layout (bytes, 16B-aligned):
  char* ws = (char*)d_ws;
  unsigned short* Xbf  = (unsigned short*)(ws);                          // 16,777,216 B
  unsigned short* W1bf = (unsigned short*)(ws + 16777216);               //  2,097,152 B
  unsigned short* W2bf = (unsigned short*)(ws + 16777216 + 2097152);     //     32,768 B
  unsigned short* W3bf = (unsigned short*)(ws + 16777216 + 2097152 + 32768);
  float*          s_ws = (float*)(ws + 16777216 + 2097152 + 65536);      //     32,768 B

  s6_convert<<<2312, 256, 0, stream>>>(x, W1, W2, W3, Xbf, W1bf, W2bf, W3bf);
  s6_s_kernel<<<128, 256, 0, stream>>>(Xbf, W2bf, b2, W3bf, b3, s_ws);
  s6_main_kernel<<<512, 256, 0, stream>>>(Xbf, W1bf, x, b1, s_ws, (float*)d_out);
}

// Round 3
// 59.143 us; speedup vs baseline: 1.2968x; 1.2968x over previous
//
#include <hip/hip_runtime.h>
#include <hip/hip_bf16.h>

typedef __attribute__((ext_vector_type(8))) short bf16x8;
typedef __attribute__((ext_vector_type(8))) unsigned short u16x8;
typedef __attribute__((ext_vector_type(4))) float f32x4;

#define DDIM 1024
#define BM 128
#define BN 128
#define BK 64   // 16 K-tiles

__device__ __forceinline__ void gload_lds16(const void* g, void* l) {
  __builtin_amdgcn_global_load_lds((const __attribute__((address_space(1))) void*)g,
                                   (__attribute__((address_space(3))) void*)l,
                                   16, 0, 0);
}

__device__ __forceinline__ unsigned short f2bf(float f) {
  unsigned int u = __float_as_uint(f);
  unsigned int r = (u + 0x7FFFu + ((u >> 16) & 1u)) >> 16;   // RNE
  return (unsigned short)r;
}

// Convert f32 rows -> bf16 rows into workspace.
// Row space: [0,8192)=X, [8192,9216)=W1, [9216,9232)=W2, [9232,9248)=W3.
__global__ __launch_bounds__(256) void s6_convert(
    const float* __restrict__ X, const float* __restrict__ W1,
    const float* __restrict__ W2, const float* __restrict__ W3,
    unsigned short* __restrict__ Xbf, unsigned short* __restrict__ W1bf,
    unsigned short* __restrict__ W2bf, unsigned short* __restrict__ W3bf)
{
  const int wid = threadIdx.x >> 6, lane = threadIdx.x & 63;
  const int row = blockIdx.x * 4 + wid;
  const float* src;
  unsigned short* dst;
  if (row < 8192)      { src = X  + (size_t)row * DDIM;        dst = Xbf  + (size_t)row * DDIM; }
  else if (row < 9216) { int r = row - 8192; src = W1 + (size_t)r * DDIM; dst = W1bf + (size_t)r * DDIM; }
  else if (row < 9232) { int r = row - 9216; src = W2 + (size_t)r * DDIM; dst = W2bf + (size_t)r * DDIM; }
  else                 { int r = row - 9232; src = W3 + (size_t)r * DDIM; dst = W3bf + (size_t)r * DDIM; }

  const float4* s4 = reinterpret_cast<const float4*>(src + lane * 16);
  unsigned short u[16];
  #pragma unroll
  for (int j = 0; j < 4; ++j) {
    float4 v = s4[j];
    u[j*4+0] = f2bf(v.x); u[j*4+1] = f2bf(v.y);
    u[j*4+2] = f2bf(v.z); u[j*4+3] = f2bf(v.w);
  }
  u16x8* d8 = reinterpret_cast<u16x8*>(dst + lane * 16);
  u16x8 lo, hi;
  #pragma unroll
  for (int j = 0; j < 8; ++j) { lo[j] = u[j]; hi[j] = u[j + 8]; }
  d8[0] = lo; d8[1] = hi;
}

// s[r] = sum_n (x[r]·W2[n] + b2[n]) * (x[r]·W3[n] + b3[n]); bf16 MFMA.
__global__ __launch_bounds__(256) void s6_s_kernel(
    const unsigned short* __restrict__ Xbf,
    const unsigned short* __restrict__ W2bf,
    const float* __restrict__ b2,
    const unsigned short* __restrict__ W3bf,
    const float* __restrict__ b3,
    float* __restrict__ s_out)
{
  const int wid  = threadIdx.x >> 6;
  const int lane = threadIdx.x & 63;
  const int grp  = blockIdx.x * 4 + wid;     // 512 groups of 16 rows
  const int r0   = grp * 16;
  const int row  = lane & 15;
  const int koff = (lane >> 4) * 8;

  const f32x4 z4 = {0.f, 0.f, 0.f, 0.f};
  f32x4 accB = z4, accC = z4;

  const unsigned short* xp  = Xbf  + (size_t)(r0 + row) * DDIM + koff;
  const unsigned short* w2p = W2bf + (size_t)row * DDIM + koff;
  const unsigned short* w3p = W3bf + (size_t)row * DDIM + koff;

  #pragma unroll 4
  for (int k = 0; k < DDIM; k += 32) {
    bf16x8 a  = *reinterpret_cast<const bf16x8*>(xp  + k);
    bf16x8 f2 = *reinterpret_cast<const bf16x8*>(w2p + k);
    bf16x8 f3 = *reinterpret_cast<const bf16x8*>(w3p + k);
    accB = __builtin_amdgcn_mfma_f32_16x16x32_bf16(a, f2, accB, 0, 0, 0);
    accC = __builtin_amdgcn_mfma_f32_16x16x32_bf16(a, f3, accC, 0, 0, 0);
  }

  const int col = lane & 15;
  const float bb = b2[col];
  const float cb = b3[col];
  float p[4];
  #pragma unroll
  for (int q = 0; q < 4; ++q) p[q] = (accB[q] + bb) * (accC[q] + cb);
  #pragma unroll
  for (int msk = 1; msk < 16; msk <<= 1) {
    #pragma unroll
    for (int q = 0; q < 4; ++q) p[q] += __shfl_xor(p[q], msk, 64);
  }
  if (col == 0) {
    const int rbase = r0 + (lane >> 4) * 4;
    #pragma unroll
    for (int q = 0; q < 4; ++q) s_out[rbase + q] = p[q];
  }
}

// y[r][e] = x[r][e] * s[r] * softplus( sum_d x[r][d]*W1[e][d] + b1[e] )
// 2-phase pipelined double-buffer + chunk-XOR swizzle (pre-swizzled source).
__global__ __launch_bounds__(256) void s6_main_kernel(
    const unsigned short* __restrict__ Xbf,
    const unsigned short* __restrict__ W1bf,
    const float* __restrict__ Xf32,
    const float* __restrict__ b1,
    const float* __restrict__ s_in,
    float* __restrict__ Y)
{
  // Per buffer: A tile 128x64 (8192 elems) then B tile 128x64. Two buffers.
  __shared__ __align__(16) unsigned short lds[2 * 2 * 8192];   // 64 KiB

  const int tid  = threadIdx.x;
  const int wid  = tid >> 6;
  const int lane = tid & 63;
  const int rb   = blockIdx.x >> 3;   // 64 row-blocks
  const int cb   = blockIdx.x & 7;    // 8 col-blocks
  const int row0 = rb * BM;
  const int col0 = cb * BN;
  const int wr = wid >> 1, wc = wid & 1;   // 2x2 waves, 64x64 each

  const f32x4 z4 = {0.f, 0.f, 0.f, 0.f};
  f32x4 acc[4][4];
  #pragma unroll
  for (int i = 0; i < 4; ++i)
    #pragma unroll
    for (int j = 0; j < 4; ++j)
      acc[i][j] = z4;

  // ---- staging geometry (swizzled source, linear LDS dest) ----
  // LDS slot s = seg*256 + wid*64 + lane  ->  (row = s>>3, slot_ch = s&7).
  // slot holds data chunk  data_ch = slot_ch ^ (row&7).
  // For thread (wid,lane): row = seg*32 + wid*8 + (lane>>3); row&7 = lane>>3;
  // slot_ch = lane&7; data_ch = (lane&7) ^ (lane>>3).
  const int srow  = wid * 8 + (lane >> 3);                // + seg*32
  const int sdch  = (lane & 7) ^ (lane >> 3);
  const unsigned short* gaBase = Xbf  + (size_t)(row0 + srow) * DDIM + sdch * 8;
  const unsigned short* gbBase = W1bf + (size_t)(col0 + srow) * DDIM + sdch * 8;

  const int fr = lane & 15;           // fragment row within 16
  // read swizzle: want data chunk c = (lane>>4) + ks*4 of row r (r&7 == fr&7):
  // LDS elem offset = r*64 + ((c ^ (fr&7)) * 8)
  const int swz0 = (((lane >> 4) + 0) ^ (fr & 7)) * 8;
  const int swz1 = (((lane >> 4) + 4) ^ (fr & 7)) * 8;

#define STAGE(buf, ktElem) do {                                                \
    const unsigned short* sa_ = gaBase + (ktElem);                             \
    const unsigned short* sb_ = gbBase + (ktElem);                             \
    unsigned short* la_ = &lds[(buf) * 16384 + wid * 512];                     \
    unsigned short* lb_ = &lds[(buf) * 16384 + 8192 + wid * 512];              \
    _Pragma("unroll")                                                          \
    for (int seg = 0; seg < 4; ++seg) {                                        \
      gload_lds16(sa_ + seg * 32 * DDIM, la_ + seg * 2048);                    \
      gload_lds16(sb_ + seg * 32 * DDIM, lb_ + seg * 2048);                    \
    }                                                                          \
  } while (0)

  STAGE(0, 0);
  __syncthreads();                    // drains vmcnt(0)

  for (int t = 0; t < 16; ++t) {
    const int cur = t & 1;
    if (t < 15) STAGE(cur ^ 1, (t + 1) * BK);    // async prefetch, in flight across compute

    const unsigned short* Al = &lds[cur * 16384];
    const unsigned short* Bl = &lds[cur * 16384 + 8192];

    #pragma unroll
    for (int ks = 0; ks < 2; ++ks) {
      const int swz = ks ? swz1 : swz0;
      bf16x8 af[4], bfr[4];
      #pragma unroll
      for (int m = 0; m < 4; ++m)
        af[m] = *reinterpret_cast<const bf16x8*>(&Al[(wr * 64 + m * 16 + fr) * BK + swz]);
      #pragma unroll
      for (int n = 0; n < 4; ++n)
        bfr[n] = *reinterpret_cast<const bf16x8*>(&Bl[(wc * 64 + n * 16 + fr) * BK + swz]);
      #pragma unroll
      for (int m = 0; m < 4; ++m)
        #pragma unroll
        for (int n = 0; n < 4; ++n)
          acc[m][n] = __builtin_amdgcn_mfma_f32_16x16x32_bf16(af[m], bfr[n], acc[m][n], 0, 0, 0);
    }
    __syncthreads();                  // drains vmcnt (prefetch) + lgkm; next iter safe
  }
#undef STAGE

  // Epilogue: D mapping col=lane&15, row=(lane>>4)*4+reg.
  const int orow = (lane >> 4) * 4;
  #pragma unroll
  for (int m = 0; m < 4; ++m) {
    #pragma unroll
    for (int q = 0; q < 4; ++q) {
      const int gr = row0 + wr * 64 + m * 16 + orow + q;
      const float sv = s_in[gr];
      const size_t rbase = (size_t)gr * DDIM;
      #pragma unroll
      for (int n = 0; n < 4; ++n) {
        const int gc = col0 + wc * 64 + n * 16 + fr;
        const float z  = acc[m][n][q] + b1[gc];
        const float sp = fmaxf(z, 0.f) + __logf(1.f + __expf(-fabsf(z)));  // softplus
        const float xv = Xf32[rbase + gc];
        Y[rbase + gc] = xv * sv * sp;
      }
    }
  }
}

extern "C" void kernel_launch(void* const* d_in, const int* in_sizes, int n_in,
                              void* d_out, int out_size, void* d_ws, size_t ws_size,
                              hipStream_t stream) {
  const float* x  = (const float*)d_in[0];
  const float* W1 = (const float*)d_in[1];
  const float* b1 = (const float*)d_in[2];
  const float* W2 = (const float*)d_in[3];
  const float* b2 = (const float*)d_in[4];
  const float* W3 = (const float*)d_in[5];
  const float* b3 = (const float*)d_in[6];
  // d_in[7] = A is provably unused (h is zero-initialized in the reference).

  char* ws = (char*)d_ws;
  unsigned short* Xbf  = (unsigned short*)(ws);                          // 16,777,216 B
  unsigned short* W1bf = (unsigned short*)(ws + 16777216);               //  2,097,152 B
  unsigned short* W2bf = (unsigned short*)(ws + 16777216 + 2097152);     //     32,768 B
  unsigned short* W3bf = (unsigned short*)(ws + 16777216 + 2097152 + 32768);
  float*          s_ws = (float*)(ws + 16777216 + 2097152 + 65536);      //     32,768 B

  s6_convert<<<2312, 256, 0, stream>>>(x, W1, W2, W3, Xbf, W1bf, W2bf, W3bf);
  s6_s_kernel<<<128, 256, 0, stream>>>(Xbf, W2bf, b2, W3bf, b3, s_ws);
  s6_main_kernel<<<512, 256, 0, stream>>>(Xbf, W1bf, x, b1, s_ws, (float*)d_out);
}

// Round 4
// 51.092 us; speedup vs baseline: 1.5011x; 1.1576x over previous
//
#include <hip/hip_runtime.h>
#include <hip/hip_bf16.h>

typedef __attribute__((ext_vector_type(8))) short bf16x8;
typedef __attribute__((ext_vector_type(8))) unsigned short u16x8;
typedef __attribute__((ext_vector_type(4))) float f32x4;

#define DDIM 1024
#define BM 128
#define BN 128
#define BK 64   // 16 K-tiles

__device__ __forceinline__ void gload_lds16(const void* g, void* l) {
  __builtin_amdgcn_global_load_lds((const __attribute__((address_space(1))) void*)g,
                                   (__attribute__((address_space(3))) void*)l,
                                   16, 0, 0);
}

__device__ __forceinline__ unsigned short f2bf(float f) {
  unsigned int u = __float_as_uint(f);
  unsigned int r = (u + 0x7FFFu + ((u >> 16) & 1u)) >> 16;   // RNE
  return (unsigned short)r;
}

// Convert f32 rows -> bf16 rows into workspace.
// Row space: [0,8192)=X, [8192,9216)=W1, [9216,9232)=W2, [9232,9248)=W3.
__global__ __launch_bounds__(256) void s6_convert(
    const float* __restrict__ X, const float* __restrict__ W1,
    const float* __restrict__ W2, const float* __restrict__ W3,
    unsigned short* __restrict__ Xbf, unsigned short* __restrict__ W1bf,
    unsigned short* __restrict__ W2bf, unsigned short* __restrict__ W3bf)
{
  const int wid = threadIdx.x >> 6, lane = threadIdx.x & 63;
  const int row = blockIdx.x * 4 + wid;
  const float* src;
  unsigned short* dst;
  if (row < 8192)      { src = X  + (size_t)row * DDIM;        dst = Xbf  + (size_t)row * DDIM; }
  else if (row < 9216) { int r = row - 8192; src = W1 + (size_t)r * DDIM; dst = W1bf + (size_t)r * DDIM; }
  else if (row < 9232) { int r = row - 9216; src = W2 + (size_t)r * DDIM; dst = W2bf + (size_t)r * DDIM; }
  else                 { int r = row - 9232; src = W3 + (size_t)r * DDIM; dst = W3bf + (size_t)r * DDIM; }

  const float4* s4 = reinterpret_cast<const float4*>(src + lane * 16);
  unsigned short u[16];
  #pragma unroll
  for (int j = 0; j < 4; ++j) {
    float4 v = s4[j];
    u[j*4+0] = f2bf(v.x); u[j*4+1] = f2bf(v.y);
    u[j*4+2] = f2bf(v.z); u[j*4+3] = f2bf(v.w);
  }
  u16x8* d8 = reinterpret_cast<u16x8*>(dst + lane * 16);
  u16x8 lo, hi;
  #pragma unroll
  for (int j = 0; j < 8; ++j) { lo[j] = u[j]; hi[j] = u[j + 8]; }
  d8[0] = lo; d8[1] = hi;
}

// s[r] = sum_n (x[r]·W2[n] + b2[n]) * (x[r]·W3[n] + b3[n]); bf16 MFMA.
// 2 waves/block, 256 blocks (1 block/CU).
__global__ __launch_bounds__(128) void s6_s_kernel(
    const unsigned short* __restrict__ Xbf,
    const unsigned short* __restrict__ W2bf,
    const float* __restrict__ b2,
    const unsigned short* __restrict__ W3bf,
    const float* __restrict__ b3,
    float* __restrict__ s_out)
{
  const int wid  = threadIdx.x >> 6;
  const int lane = threadIdx.x & 63;
  const int grp  = blockIdx.x * 2 + wid;     // 512 groups of 16 rows
  const int r0   = grp * 16;
  const int row  = lane & 15;
  const int koff = (lane >> 4) * 8;

  const f32x4 z4 = {0.f, 0.f, 0.f, 0.f};
  f32x4 accB = z4, accC = z4;

  const unsigned short* xp  = Xbf  + (size_t)(r0 + row) * DDIM + koff;
  const unsigned short* w2p = W2bf + (size_t)row * DDIM + koff;
  const unsigned short* w3p = W3bf + (size_t)row * DDIM + koff;

  #pragma unroll 4
  for (int k = 0; k < DDIM; k += 32) {
    bf16x8 a  = *reinterpret_cast<const bf16x8*>(xp  + k);
    bf16x8 f2 = *reinterpret_cast<const bf16x8*>(w2p + k);
    bf16x8 f3 = *reinterpret_cast<const bf16x8*>(w3p + k);
    accB = __builtin_amdgcn_mfma_f32_16x16x32_bf16(a, f2, accB, 0, 0, 0);
    accC = __builtin_amdgcn_mfma_f32_16x16x32_bf16(a, f3, accC, 0, 0, 0);
  }

  const int col = lane & 15;
  const float bb = b2[col];
  const float cb = b3[col];
  float p[4];
  #pragma unroll
  for (int q = 0; q < 4; ++q) p[q] = (accB[q] + bb) * (accC[q] + cb);
  #pragma unroll
  for (int msk = 1; msk < 16; msk <<= 1) {
    #pragma unroll
    for (int q = 0; q < 4; ++q) p[q] += __shfl_xor(p[q], msk, 64);
  }
  if (col == 0) {
    const int rbase = r0 + (lane >> 4) * 4;
    #pragma unroll
    for (int q = 0; q < 4; ++q) s_out[rbase + q] = p[q];
  }
}

// y[r][e] = x[r][e] * s[r] * softplus( sum_d x[r][d]*W1[e][d] + b1[e] )
// 2-phase pipelined double-buffer + chunk-XOR swizzle + XCD-chunked tiles.
__global__ __launch_bounds__(256) void s6_main_kernel(
    const unsigned short* __restrict__ Xbf,
    const unsigned short* __restrict__ W1bf,
    const float* __restrict__ b1,
    const float* __restrict__ s_in,
    float* __restrict__ Y)
{
  __shared__ __align__(16) unsigned short lds[2 * 2 * 8192];   // 64 KiB

  const int tid  = threadIdx.x;
  const int wid  = tid >> 6;
  const int lane = tid & 63;
  // XCD-chunked swizzle: XCD x (= bid%8) owns tiles [x*64,(x+1)*64) ->
  // row-panels rb in [x*8,(x+1)*8): all 8 col-blocks of a panel share one L2.
  const int tile = (blockIdx.x & 7) * 64 + (blockIdx.x >> 3);
  const int rb   = tile >> 3;         // 64 row-blocks
  const int cb   = tile & 7;          // 8 col-blocks
  const int row0 = rb * BM;
  const int col0 = cb * BN;
  const int wr = wid >> 1, wc = wid & 1;   // 2x2 waves, 64x64 each

  const f32x4 z4 = {0.f, 0.f, 0.f, 0.f};
  f32x4 acc[4][4];
  #pragma unroll
  for (int i = 0; i < 4; ++i)
    #pragma unroll
    for (int j = 0; j < 4; ++j)
      acc[i][j] = z4;

  // ---- staging geometry (swizzled source, linear LDS dest) ----
  // LDS slot s = seg*256 + wid*64 + lane -> (row = s>>3, slot_ch = s&7);
  // slot holds data chunk (slot_ch ^ (row&7)).
  const int srow  = wid * 8 + (lane >> 3);                // + seg*32
  const int sdch  = (lane & 7) ^ (lane >> 3);
  const unsigned short* gaBase = Xbf  + (size_t)(row0 + srow) * DDIM + sdch * 8;
  const unsigned short* gbBase = W1bf + (size_t)(col0 + srow) * DDIM + sdch * 8;

  const int fr = lane & 15;           // fragment row within 16
  const int swz0 = (((lane >> 4) + 0) ^ (fr & 7)) * 8;
  const int swz1 = (((lane >> 4) + 4) ^ (fr & 7)) * 8;

#define STAGE(buf, ktElem) do {                                                \
    const unsigned short* sa_ = gaBase + (ktElem);                             \
    const unsigned short* sb_ = gbBase + (ktElem);                             \
    unsigned short* la_ = &lds[(buf) * 16384 + wid * 512];                     \
    unsigned short* lb_ = &lds[(buf) * 16384 + 8192 + wid * 512];              \
    _Pragma("unroll")                                                          \
    for (int seg = 0; seg < 4; ++seg) {                                        \
      gload_lds16(sa_ + seg * 32 * DDIM, la_ + seg * 2048);                    \
      gload_lds16(sb_ + seg * 32 * DDIM, lb_ + seg * 2048);                    \
    }                                                                          \
  } while (0)

  STAGE(0, 0);
  __syncthreads();

  for (int t = 0; t < 16; ++t) {
    const int cur = t & 1;
    if (t < 15) STAGE(cur ^ 1, (t + 1) * BK);    // async prefetch over compute

    const unsigned short* Al = &lds[cur * 16384];
    const unsigned short* Bl = &lds[cur * 16384 + 8192];

    #pragma unroll
    for (int ks = 0; ks < 2; ++ks) {
      const int swz = ks ? swz1 : swz0;
      bf16x8 af[4], bfr[4];
      #pragma unroll
      for (int m = 0; m < 4; ++m)
        af[m] = *reinterpret_cast<const bf16x8*>(&Al[(wr * 64 + m * 16 + fr) * BK + swz]);
      #pragma unroll
      for (int n = 0; n < 4; ++n)
        bfr[n] = *reinterpret_cast<const bf16x8*>(&Bl[(wc * 64 + n * 16 + fr) * BK + swz]);
      #pragma unroll
      for (int m = 0; m < 4; ++m)
        #pragma unroll
        for (int n = 0; n < 4; ++n)
          acc[m][n] = __builtin_amdgcn_mfma_f32_16x16x32_bf16(af[m], bfr[n], acc[m][n], 0, 0, 0);
    }
    __syncthreads();
  }
#undef STAGE

  // Epilogue: D mapping col=lane&15, row=(lane>>4)*4+reg. x from Xbf (L2/L3-hot).
  const int orow = (lane >> 4) * 4;
  #pragma unroll
  for (int m = 0; m < 4; ++m) {
    #pragma unroll
    for (int q = 0; q < 4; ++q) {
      const int gr = row0 + wr * 64 + m * 16 + orow + q;
      const float sv = s_in[gr];
      const size_t rbase = (size_t)gr * DDIM;
      #pragma unroll
      for (int n = 0; n < 4; ++n) {
        const int gc = col0 + wc * 64 + n * 16 + fr;
        const float z  = acc[m][n][q] + b1[gc];
        const float sp = fmaxf(z, 0.f) + __logf(1.f + __expf(-fabsf(z)));  // softplus
        const float xv = __bfloat162float(*(const __hip_bfloat16*)&Xbf[rbase + gc]);
        Y[rbase + gc] = xv * sv * sp;
      }
    }
  }
}

extern "C" void kernel_launch(void* const* d_in, const int* in_sizes, int n_in,
                              void* d_out, int out_size, void* d_ws, size_t ws_size,
                              hipStream_t stream) {
  const float* x  = (const float*)d_in[0];
  const float* W1 = (const float*)d_in[1];
  const float* b1 = (const float*)d_in[2];
  const float* W2 = (const float*)d_in[3];
  const float* b2 = (const float*)d_in[4];
  const float* W3 = (const float*)d_in[5];
  const float* b3 = (const float*)d_in[6];
  // d_in[7] = A is provably unused (h is zero-initialized in the reference).

  char* ws = (char*)d_ws;
  unsigned short* Xbf  = (unsigned short*)(ws);                          // 16,777,216 B
  unsigned short* W1bf = (unsigned short*)(ws + 16777216);               //  2,097,152 B
  unsigned short* W2bf = (unsigned short*)(ws + 16777216 + 2097152);     //     32,768 B
  unsigned short* W3bf = (unsigned short*)(ws + 16777216 + 2097152 + 32768);
  float*          s_ws = (float*)(ws + 16777216 + 2097152 + 65536);      //     32,768 B

  s6_convert<<<2312, 256, 0, stream>>>(x, W1, W2, W3, Xbf, W1bf, W2bf, W3bf);
  s6_s_kernel<<<256, 128, 0, stream>>>(Xbf, W2bf, b2, W3bf, b3, s_ws);
  s6_main_kernel<<<512, 256, 0, stream>>>(Xbf, W1bf, b1, s_ws, (float*)d_out);
}

// Round 5
// 46.428 us; speedup vs baseline: 1.6519x; 1.1005x over previous
//
#include <hip/hip_runtime.h>
#include <hip/hip_bf16.h>

typedef __attribute__((ext_vector_type(8))) short bf16x8;
typedef __attribute__((ext_vector_type(8))) unsigned short u16x8;
typedef __attribute__((ext_vector_type(4))) float f32x4;

#define DDIM 1024
#define BM 128
#define BN 128
#define BK 64   // 16 K-tiles

__device__ __forceinline__ void gload_lds16(const void* g, void* l) {
  __builtin_amdgcn_global_load_lds((const __attribute__((address_space(1))) void*)g,
                                   (__attribute__((address_space(3))) void*)l,
                                   16, 0, 0);
}

__device__ __forceinline__ unsigned short f2bf(float f) {
  unsigned int u = __float_as_uint(f);
  unsigned int r = (u + 0x7FFFu + ((u >> 16) & 1u)) >> 16;   // RNE
  return (unsigned short)r;
}

// Convert f32 rows -> bf16 rows into workspace.
// Row space: [0,8192)=X, [8192,9216)=W1, [9216,9232)=W2, [9232,9248)=W3.
__global__ __launch_bounds__(256) void s6_convert(
    const float* __restrict__ X, const float* __restrict__ W1,
    const float* __restrict__ W2, const float* __restrict__ W3,
    unsigned short* __restrict__ Xbf, unsigned short* __restrict__ W1bf,
    unsigned short* __restrict__ W2bf, unsigned short* __restrict__ W3bf)
{
  const int wid = threadIdx.x >> 6, lane = threadIdx.x & 63;
  const int row = blockIdx.x * 4 + wid;
  const float* src;
  unsigned short* dst;
  if (row < 8192)      { src = X  + (size_t)row * DDIM;        dst = Xbf  + (size_t)row * DDIM; }
  else if (row < 9216) { int r = row - 8192; src = W1 + (size_t)r * DDIM; dst = W1bf + (size_t)r * DDIM; }
  else if (row < 9232) { int r = row - 9216; src = W2 + (size_t)r * DDIM; dst = W2bf + (size_t)r * DDIM; }
  else                 { int r = row - 9232; src = W3 + (size_t)r * DDIM; dst = W3bf + (size_t)r * DDIM; }

  const float4* s4 = reinterpret_cast<const float4*>(src + lane * 16);
  unsigned short u[16];
  #pragma unroll
  for (int j = 0; j < 4; ++j) {
    float4 v = s4[j];
    u[j*4+0] = f2bf(v.x); u[j*4+1] = f2bf(v.y);
    u[j*4+2] = f2bf(v.z); u[j*4+3] = f2bf(v.w);
  }
  u16x8* d8 = reinterpret_cast<u16x8*>(dst + lane * 16);
  u16x8 lo, hi;
  #pragma unroll
  for (int j = 0; j < 8; ++j) { lo[j] = u[j]; hi[j] = u[j + 8]; }
  d8[0] = lo; d8[1] = hi;
}

// Fused: y[r][e] = x[r][e] * softplus((x@W1^T)[r][e]+b1[e]) * s[r],
//   s[r] = sum_n ((x@W2^T)[r][n]+b2[n]) * ((x@W3^T)[r][n]+b3[n])
// 2-phase double-buffer, counted-vmcnt pipeline, chunk-XOR swizzle, XCD tiles.
__global__ __launch_bounds__(256) void s6_main_fused(
    const unsigned short* __restrict__ Xbf,
    const unsigned short* __restrict__ W1bf,
    const unsigned short* __restrict__ W2bf,
    const unsigned short* __restrict__ W3bf,
    const float* __restrict__ b1,
    const float* __restrict__ b2,
    const float* __restrict__ b3,
    unsigned short* __restrict__ XbfDummy,   // keep signature simple
    float* __restrict__ Y)
{
  // LDS: A[2][8192], B[2][8192], W2[2][1024], W3[2][1024]  = 72 KiB (bf16)
  __shared__ __align__(16) unsigned short lds[2 * 8192 + 2 * 8192 + 2 * 1024 + 2 * 1024];
  unsigned short* Ab = lds;                 // [2][8192]
  unsigned short* Bb = lds + 16384;         // [2][8192]
  unsigned short* W2b = lds + 32768;        // [2][1024]
  unsigned short* W3b = lds + 34816;        // [2][1024]

  const int tid  = threadIdx.x;
  const int wid  = tid >> 6;
  const int lane = tid & 63;
  // XCD-chunked: XCD x (= bid%8) owns tiles [x*64,(x+1)*64) -> 8 row-panels.
  const int tile = (blockIdx.x & 7) * 64 + (blockIdx.x >> 3);
  const int rb   = tile >> 3;
  const int cb   = tile & 7;
  const int row0 = rb * BM;
  const int col0 = cb * BN;
  const int wr = wid >> 1, wc = wid & 1;    // 2x2 waves, 64x64 each

  const f32x4 z4 = {0.f, 0.f, 0.f, 0.f};
  f32x4 acc[4][4];
  #pragma unroll
  for (int i = 0; i < 4; ++i)
    #pragma unroll
    for (int j = 0; j < 4; ++j)
      acc[i][j] = z4;
  f32x4 accS[4] = {z4, z4, z4, z4};         // projection acc (wc=0:W2, wc=1:W3)

  // ---- staging geometry (swizzled global source, linear LDS dest) ----
  // slot chunk s holds data chunk (s&7) ^ ((s>>3)&7); per thread:
  const int srow  = wid * 8 + (lane >> 3);                 // + seg*32
  const int sdch  = (lane & 7) ^ (lane >> 3);
  const unsigned short* gaBase = Xbf  + (size_t)(row0 + srow) * DDIM + sdch * 8;
  const unsigned short* gbBase = W1bf + (size_t)(col0 + srow) * DDIM + sdch * 8;
  // W2/W3 tile (16x64): waves 0,1 stage W2; waves 2,3 stage W3.
  const int wrow = (wid & 1) * 8 + (lane >> 3);
  const unsigned short* gwBase = (wid < 2 ? W2bf : W3bf) + (size_t)wrow * DDIM + sdch * 8;

  const int fr = lane & 15;                 // fragment row within 16
  const int swz0 = (((lane >> 4) + 0) ^ (fr & 7)) * 8;
  const int swz1 = (((lane >> 4) + 4) ^ (fr & 7)) * 8;

#define STAGE(buf, ktElem) do {                                                \
    const unsigned short* sa_ = gaBase + (ktElem);                             \
    const unsigned short* sb_ = gbBase + (ktElem);                             \
    unsigned short* la_ = Ab + (buf) * 8192 + wid * 512;                       \
    unsigned short* lb_ = Bb + (buf) * 8192 + wid * 512;                       \
    _Pragma("unroll")                                                          \
    for (int seg = 0; seg < 4; ++seg) {                                        \
      gload_lds16(sa_ + seg * 32 * DDIM, la_ + seg * 2048);                    \
      gload_lds16(sb_ + seg * 32 * DDIM, lb_ + seg * 2048);                    \
    }                                                                          \
    unsigned short* lw_ = (wid < 2 ? W2b : W3b) + (buf) * 1024 + (wid & 1) * 512; \
    gload_lds16(gwBase + (ktElem), lw_);                                       \
  } while (0)

  STAGE(0, 0);

  for (int t = 0; t < 16; ++t) {
    const int cur = t & 1;
    if (t < 15) {
      STAGE(cur ^ 1, (t + 1) * BK);         // prefetch stays in flight over compute
      asm volatile("s_waitcnt vmcnt(9)" ::: "memory");   // cur's 9 loads done
    } else {
      asm volatile("s_waitcnt vmcnt(0)" ::: "memory");
    }
    __builtin_amdgcn_s_barrier();           // all waves' slices staged
    __builtin_amdgcn_sched_barrier(0);      // no ds_read hoisting above barrier

    const unsigned short* Al = Ab + cur * 8192;
    const unsigned short* Bl = Bb + cur * 8192;
    const unsigned short* Wl = (wc == 0 ? W2b : W3b) + cur * 1024;

    #pragma unroll
    for (int ks = 0; ks < 2; ++ks) {
      const int swz = ks ? swz1 : swz0;
      bf16x8 af[4], bfr[4], wf;
      #pragma unroll
      for (int m = 0; m < 4; ++m)
        af[m] = *reinterpret_cast<const bf16x8*>(&Al[(wr * 64 + m * 16 + fr) * BK + swz]);
      #pragma unroll
      for (int n = 0; n < 4; ++n)
        bfr[n] = *reinterpret_cast<const bf16x8*>(&Bl[(wc * 64 + n * 16 + fr) * BK + swz]);
      wf = *reinterpret_cast<const bf16x8*>(&Wl[fr * BK + swz]);
      #pragma unroll
      for (int m = 0; m < 4; ++m) {
        #pragma unroll
        for (int n = 0; n < 4; ++n)
          acc[m][n] = __builtin_amdgcn_mfma_f32_16x16x32_bf16(af[m], bfr[n], acc[m][n], 0, 0, 0);
        accS[m] = __builtin_amdgcn_mfma_f32_16x16x32_bf16(af[m], wf, accS[m], 0, 0, 0);
      }
    }
    __builtin_amdgcn_s_barrier();           // all reads of cur done -> next overwrite safe
  }
#undef STAGE

  // ---- s[r] via cross-wave exchange (reuse LDS; stride 17 = conflict-free) ----
  __syncthreads();
  float* sEx = (float*)lds;                 // 256 rows * 17 f32 = 17 KiB < 72 KiB
  const int n_  = lane & 15;
  const int rgp = (lane >> 4) * 4;
  const float bSelf = (wc == 0 ? b2[n_] : b3[n_]);
  #pragma unroll
  for (int m = 0; m < 4; ++m)
    #pragma unroll
    for (int q = 0; q < 4; ++q)
      sEx[(wc * 128 + wr * 64 + m * 16 + rgp + q) * 17 + n_] = accS[m][q] + bSelf;
  __syncthreads();

  float sv[4][4];
  #pragma unroll
  for (int m = 0; m < 4; ++m) {
    #pragma unroll
    for (int q = 0; q < 4; ++q) {
      const float other = sEx[((wc ^ 1) * 128 + wr * 64 + m * 16 + rgp + q) * 17 + n_];
      float p = (accS[m][q] + bSelf) * other;
      p += __shfl_xor(p, 1, 64);
      p += __shfl_xor(p, 2, 64);
      p += __shfl_xor(p, 4, 64);
      p += __shfl_xor(p, 8, 64);            // butterfly: all 16 lanes hold sum_n
      sv[m][q] = p;
    }
  }

  // ---- epilogue: D mapping col=lane&15, row=(lane>>4)*4+reg ----
  #pragma unroll
  for (int m = 0; m < 4; ++m) {
    #pragma unroll
    for (int q = 0; q < 4; ++q) {
      const int gr = row0 + wr * 64 + m * 16 + rgp + q;
      const float svv = sv[m][q];
      const size_t rbase = (size_t)gr * DDIM;
      #pragma unroll
      for (int n = 0; n < 4; ++n) {
        const int gc = col0 + wc * 64 + n * 16 + fr;
        const float z  = acc[m][n][q] + b1[gc];
        const float sp = fmaxf(z, 0.f) + __logf(1.f + __expf(-fabsf(z)));  // softplus
        const float xv = __bfloat162float(*(const __hip_bfloat16*)&Xbf[rbase + gc]);
        Y[rbase + gc] = xv * svv * sp;
      }
    }
  }
}

extern "C" void kernel_launch(void* const* d_in, const int* in_sizes, int n_in,
                              void* d_out, int out_size, void* d_ws, size_t ws_size,
                              hipStream_t stream) {
  const float* x  = (const float*)d_in[0];
  const float* W1 = (const float*)d_in[1];
  const float* b1 = (const float*)d_in[2];
  const float* W2 = (const float*)d_in[3];
  const float* b2 = (const float*)d_in[4];
  const float* W3 = (const float*)d_in[5];
  const float* b3 = (const float*)d_in[6];
  // d_in[7] = A is provably unused (h is zero-initialized in the reference).

  char* ws = (char*)d_ws;
  unsigned short* Xbf  = (unsigned short*)(ws);                          // 16,777,216 B
  unsigned short* W1bf = (unsigned short*)(ws + 16777216);               //  2,097,152 B
  unsigned short* W2bf = (unsigned short*)(ws + 16777216 + 2097152);     //     32,768 B
  unsigned short* W3bf = (unsigned short*)(ws + 16777216 + 2097152 + 32768);

  s6_convert<<<2312, 256, 0, stream>>>(x, W1, W2, W3, Xbf, W1bf, W2bf, W3bf);
  s6_main_fused<<<512, 256, 0, stream>>>(Xbf, W1bf, W2bf, W3bf, b1, b2, b3,
                                         nullptr, (float*)d_out);
}

// Round 6
// 44.351 us; speedup vs baseline: 1.7292x; 1.0468x over previous
//
#include <hip/hip_runtime.h>
#include <hip/hip_bf16.h>

typedef __attribute__((ext_vector_type(8))) short bf16x8;
typedef __attribute__((ext_vector_type(8))) unsigned short u16x8;
typedef __attribute__((ext_vector_type(4))) float f32x4;

#define DDIM 1024
#define BM 256
#define BN 128
#define BK 64   // 16 K-steps

__device__ __forceinline__ void gload_lds16(const void* g, void* l) {
  __builtin_amdgcn_global_load_lds((const __attribute__((address_space(1))) void*)g,
                                   (__attribute__((address_space(3))) void*)l,
                                   16, 0, 0);
}

__device__ __forceinline__ unsigned short f2bf(float f) {
  unsigned int u = __float_as_uint(f);
  unsigned int r = (u + 0x7FFFu + ((u >> 16) & 1u)) >> 16;   // RNE
  return (unsigned short)r;
}

// Convert f32 rows -> bf16 rows into workspace.
__global__ __launch_bounds__(256) void s6_convert(
    const float* __restrict__ X, const float* __restrict__ W1,
    const float* __restrict__ W2, const float* __restrict__ W3,
    unsigned short* __restrict__ Xbf, unsigned short* __restrict__ W1bf,
    unsigned short* __restrict__ W2bf, unsigned short* __restrict__ W3bf)
{
  const int wid = threadIdx.x >> 6, lane = threadIdx.x & 63;
  const int row = blockIdx.x * 4 + wid;
  const float* src;
  unsigned short* dst;
  if (row < 8192)      { src = X  + (size_t)row * DDIM;        dst = Xbf  + (size_t)row * DDIM; }
  else if (row < 9216) { int r = row - 8192; src = W1 + (size_t)r * DDIM; dst = W1bf + (size_t)r * DDIM; }
  else if (row < 9232) { int r = row - 9216; src = W2 + (size_t)r * DDIM; dst = W2bf + (size_t)r * DDIM; }
  else                 { int r = row - 9232; src = W3 + (size_t)r * DDIM; dst = W3bf + (size_t)r * DDIM; }

  const float4* s4 = reinterpret_cast<const float4*>(src + lane * 16);
  unsigned short u[16];
  #pragma unroll
  for (int j = 0; j < 4; ++j) {
    float4 v = s4[j];
    u[j*4+0] = f2bf(v.x); u[j*4+1] = f2bf(v.y);
    u[j*4+2] = f2bf(v.z); u[j*4+3] = f2bf(v.w);
  }
  u16x8* d8 = reinterpret_cast<u16x8*>(dst + lane * 16);
  u16x8 lo, hi;
  #pragma unroll
  for (int j = 0; j < 8; ++j) { lo[j] = u[j]; hi[j] = u[j + 8]; }
  d8[0] = lo; d8[1] = hi;
}

// Fused GEMM + projections + softplus epilogue.
// 8 waves (2N x 4M), 256x128 tile, BK=64, 1 block/CU, counted-vmcnt prefetch.
__global__ __launch_bounds__(512, 2) void s6_main_fused(
    const unsigned short* __restrict__ Xbf,
    const unsigned short* __restrict__ W1bf,
    const unsigned short* __restrict__ W2bf,
    const unsigned short* __restrict__ W3bf,
    const float* __restrict__ b1,
    const float* __restrict__ b2,
    const float* __restrict__ b3,
    float* __restrict__ Y)
{
  // A: [2][256*64]  B+: [2][192*64]  (rows 0-127: W1 cols; 128-143: W2; 144-159: W3; 160-191 pad)
  __shared__ __align__(16) unsigned short lds[2 * 16384 + 2 * 12288];   // 112 KiB
  unsigned short* AB = lds;
  unsigned short* BB = lds + 2 * 16384;

  const int tid  = threadIdx.x;
  const int wid  = tid >> 6;
  const int lane = tid & 63;
  // XCD-chunked: XCD x owns 32 consecutive tiles = 4 row-panels x 8 col-blocks.
  const int tile = (blockIdx.x & 7) * 32 + (blockIdx.x >> 3);
  const int rb   = tile >> 3;         // 32 row-blocks
  const int cb   = tile & 7;          // 8 col-blocks
  const int row0 = rb * BM;
  const int col0 = cb * BN;
  const int wr = wid >> 1, wc = wid & 1;   // 4M x 2N waves, 64x64 each

  const f32x4 z4 = {0.f, 0.f, 0.f, 0.f};
  f32x4 acc[4][4];
  #pragma unroll
  for (int i = 0; i < 4; ++i)
    #pragma unroll
    for (int j = 0; j < 4; ++j)
      acc[i][j] = z4;
  f32x4 accS[4] = {z4, z4, z4, z4};   // projection acc (wc=0: W2, wc=1: W3)

  // ---- staging geometry (swizzled global source, linear LDS dest) ----
  // slot s = seg*512 + tid -> row = seg*64 + (tid>>3); slot chunk = tid&7;
  // slot holds data chunk (tid&7) ^ ((tid>>3)&7).
  const int srow = tid >> 3;                       // 0..63 (+seg*64)
  const int sdch = (lane & 7) ^ (lane >> 3);
  const unsigned short* gaBase = Xbf  + (size_t)(row0 + srow) * DDIM + sdch * 8;
  const unsigned short* gbBase = W1bf + (size_t)(col0 + srow) * DDIM + sdch * 8;
  // B+ seg2 source: rows 128+sub: sub<16 -> W2; <32 -> W3; else dummy (W2 again).
  const int sub = srow;
  const unsigned short* gwsrc;
  if (sub < 16)      gwsrc = W2bf + (size_t)sub * DDIM;
  else if (sub < 32) gwsrc = W3bf + (size_t)(sub - 16) * DDIM;
  else               gwsrc = W2bf + (size_t)(sub & 15) * DDIM;
  const unsigned short* gwBase = gwsrc + sdch * 8;

  const int fr = lane & 15;
  const int swz0 = (((lane >> 4) + 0) ^ (fr & 7)) * 8;
  const int swz1 = (((lane >> 4) + 4) ^ (fr & 7)) * 8;

#define STAGE(BUF, KEL) do {                                                   \
    const unsigned short* sa_ = gaBase + (KEL);                                \
    const unsigned short* sb_ = gbBase + (KEL);                                \
    unsigned short* la_ = AB + (BUF) * 16384 + wid * 512;                      \
    unsigned short* lb_ = BB + (BUF) * 12288 + wid * 512;                      \
    gload_lds16(sa_,                la_);                                      \
    gload_lds16(sa_ +  64 * DDIM,   la_ + 4096);                               \
    gload_lds16(sa_ + 128 * DDIM,   la_ + 8192);                               \
    gload_lds16(sa_ + 192 * DDIM,   la_ + 12288);                              \
    gload_lds16(sb_,                lb_);                                      \
    gload_lds16(sb_ +  64 * DDIM,   lb_ + 4096);                               \
    gload_lds16(gwBase + (KEL),     lb_ + 8192);                               \
  } while (0)

#define COMPUTE(PAR) do {                                                      \
    const unsigned short* Al = AB + (PAR) * 16384;                             \
    const unsigned short* Bl = BB + (PAR) * 12288;                             \
    bf16x8 af[4][2], bfr[4][2], wfr[2];                                        \
    _Pragma("unroll")                                                          \
    for (int m = 0; m < 4; ++m) {                                              \
      af[m][0] = *reinterpret_cast<const bf16x8*>(&Al[(wr*64 + m*16 + fr)*BK + swz0]); \
      af[m][1] = *reinterpret_cast<const bf16x8*>(&Al[(wr*64 + m*16 + fr)*BK + swz1]); \
    }                                                                          \
    _Pragma("unroll")                                                          \
    for (int n = 0; n < 4; ++n) {                                              \
      bfr[n][0] = *reinterpret_cast<const bf16x8*>(&Bl[(wc*64 + n*16 + fr)*BK + swz0]); \
      bfr[n][1] = *reinterpret_cast<const bf16x8*>(&Bl[(wc*64 + n*16 + fr)*BK + swz1]); \
    }                                                                          \
    wfr[0] = *reinterpret_cast<const bf16x8*>(&Bl[(128 + wc*16 + fr)*BK + swz0]); \
    wfr[1] = *reinterpret_cast<const bf16x8*>(&Bl[(128 + wc*16 + fr)*BK + swz1]); \
    __builtin_amdgcn_s_setprio(1);                                             \
    _Pragma("unroll")                                                          \
    for (int ks = 0; ks < 2; ++ks) {                                           \
      _Pragma("unroll")                                                        \
      for (int m = 0; m < 4; ++m) {                                            \
        _Pragma("unroll")                                                      \
        for (int n = 0; n < 4; ++n)                                            \
          acc[m][n] = __builtin_amdgcn_mfma_f32_16x16x32_bf16(af[m][ks], bfr[n][ks], acc[m][n], 0, 0, 0); \
        accS[m] = __builtin_amdgcn_mfma_f32_16x16x32_bf16(af[m][ks], wfr[ks], accS[m], 0, 0, 0); \
      }                                                                        \
    }                                                                          \
    __builtin_amdgcn_s_setprio(0);                                             \
  } while (0)

#define STEP(J, PAR) do {                                                      \
    if ((J) < 15) {                                                            \
      STAGE((PAR) ^ 1, ((J) + 1) * BK);                                        \
      asm volatile("s_waitcnt vmcnt(7)" ::: "memory");                         \
    } else {                                                                   \
      asm volatile("s_waitcnt vmcnt(0)" ::: "memory");                         \
    }                                                                          \
    __builtin_amdgcn_s_barrier();                                              \
    __builtin_amdgcn_sched_barrier(0);                                         \
    COMPUTE(PAR);                                                              \
    __builtin_amdgcn_s_barrier();                                              \
  } while (0)

  STAGE(0, 0);
  asm volatile("s_waitcnt vmcnt(0)" ::: "memory");
  __builtin_amdgcn_s_barrier();

  for (int jj = 0; jj < 16; jj += 2) {
    STEP(jj, 0);
    STEP(jj + 1, 1);
  }
#undef STEP
#undef COMPUTE
#undef STAGE

  // ---- s[r]: cross-wave exchange of the two projections (pad 17 = conflict-free) ----
  float* sEx = (float*)lds;           // [2][256][17] f32 = 68 KiB < 112 KiB
  const int n_  = lane & 15;
  const int rgp = (lane >> 4) * 4;
  const float bSelf = (wc == 0 ? b2[n_] : b3[n_]);
  #pragma unroll
  for (int m = 0; m < 4; ++m)
    #pragma unroll
    for (int q = 0; q < 4; ++q)
      sEx[(wc * 256 + wr * 64 + m * 16 + rgp + q) * 17 + n_] = accS[m][q] + bSelf;
  __syncthreads();

  float sv[4][4];
  #pragma unroll
  for (int m = 0; m < 4; ++m) {
    #pragma unroll
    for (int q = 0; q < 4; ++q) {
      const float other = sEx[((wc ^ 1) * 256 + wr * 64 + m * 16 + rgp + q) * 17 + n_];
      float p = (accS[m][q] + bSelf) * other;
      p += __shfl_xor(p, 1, 64);
      p += __shfl_xor(p, 2, 64);
      p += __shfl_xor(p, 4, 64);
      p += __shfl_xor(p, 8, 64);
      sv[m][q] = p;
    }
  }

  // ---- epilogue: D mapping col=lane&15, row=(lane>>4)*4+reg ----
  #pragma unroll
  for (int m = 0; m < 4; ++m) {
    #pragma unroll
    for (int q = 0; q < 4; ++q) {
      const int gr = row0 + wr * 64 + m * 16 + rgp + q;
      const float svv = sv[m][q];
      const size_t rbase = (size_t)gr * DDIM;
      #pragma unroll
      for (int n = 0; n < 4; ++n) {
        const int gc = col0 + wc * 64 + n * 16 + fr;
        const float z  = acc[m][n][q] + b1[gc];
        const float sp = fmaxf(z, 0.f) + __logf(1.f + __expf(-fabsf(z)));  // softplus
        const float xv = __bfloat162float(*(const __hip_bfloat16*)&Xbf[rbase + gc]);
        Y[rbase + gc] = xv * svv * sp;
      }
    }
  }
}

extern "C" void kernel_launch(void* const* d_in, const int* in_sizes, int n_in,
                              void* d_out, int out_size, void* d_ws, size_t ws_size,
                              hipStream_t stream) {
  const float* x  = (const float*)d_in[0];
  const float* W1 = (const float*)d_in[1];
  const float* b1 = (const float*)d_in[2];
  const float* W2 = (const float*)d_in[3];
  const float* b2 = (const float*)d_in[4];
  const float* W3 = (const float*)d_in[5];
  const float* b3 = (const float*)d_in[6];
  // d_in[7] = A is provably unused (h is zero-initialized in the reference).

  char* ws = (char*)d_ws;
  unsigned short* Xbf  = (unsigned short*)(ws);                          // 16,777,216 B
  unsigned short* W1bf = (unsigned short*)(ws + 16777216);               //  2,097,152 B
  unsigned short* W2bf = (unsigned short*)(ws + 16777216 + 2097152);     //     32,768 B
  unsigned short* W3bf = (unsigned short*)(ws + 16777216 + 2097152 + 32768);

  s6_convert<<<2312, 256, 0, stream>>>(x, W1, W2, W3, Xbf, W1bf, W2bf, W3bf);
  s6_main_fused<<<256, 512, 0, stream>>>(Xbf, W1bf, W2bf, W3bf, b1, b2, b3,
                                         (float*)d_out);
}